// Round 4
// baseline (253.754 us; speedup 1.0000x reference)
//
#include <hip/hip_runtime.h>
#include <hip/hip_bf16.h>
#include <cstdint>
#include <cstddef>

#define B_  64
#define T_  256
#define C_  2048
#define HS_ 128
#define N_  384

typedef __bf16 bf16x8 __attribute__((ext_vector_type(8)));
typedef float  floatx4 __attribute__((ext_vector_type(4)));

__device__ __forceinline__ unsigned short f2bf_rne(float f) {
  union { float f; unsigned int u; } v; v.f = f;
  unsigned int r = v.u + 0x7fffu + ((v.u >> 16) & 1u);
  return (unsigned short)(r >> 16);
}
__device__ __forceinline__ unsigned short f2bf(float f) {
  union { float f; unsigned int u; } v; v.f = f;
  return (unsigned short)((v.u + 0x8000u) >> 16);
}

// ---------------- Weight transpose + bf16 cast: Wt[w*128+h][c] = W_w[c][h] ---
__global__ __launch_bounds__(256) void wt_kernel(
    const float* __restrict__ Wk, const float* __restrict__ Wq,
    const float* __restrict__ Wv, unsigned short* __restrict__ Wt) {
  __shared__ float tile[32][33];
  const int w  = blockIdx.z;
  const int c0 = blockIdx.x * 32;
  const int h0 = blockIdx.y * 32;
  const float* W = (w == 0) ? Wk : (w == 1) ? Wq : Wv;
  const int tx = threadIdx.x & 31, ty = threadIdx.x >> 5;
#pragma unroll
  for (int i = 0; i < 32; i += 8)
    tile[ty + i][tx] = W[(size_t)(c0 + ty + i) * HS_ + h0 + tx];
  __syncthreads();
#pragma unroll
  for (int i = 0; i < 32; i += 8) {
    int hh = ty + i, cc = tx;
    Wt[(size_t)(w * HS_ + h0 + hh) * C_ + c0 + cc] = f2bf_rne(tile[cc][hh]);
  }
}

// ---------------- QKV GEMM v4: B streamed from L2, A via tiny LDS dbuf ------
// Grid (256 m-tiles, 2 n-halves) = 512 blocks, 4 waves. Wave tile 64m x 48n.
// Per BK=32 iter: stage A (64x32 fp32->bf16, 4KB, shared x4 waves), ONE
// barrier, B frags direct from global (Wt is 1.5MB, L2-resident), register
// double-buffered with a full iteration of latency hiding. No vmcnt-drain
// pathology: at each barrier the only in-flight vmem is last iter's (landed).
__global__ __launch_bounds__(256, 2) void qkv_gemm(
    const float* __restrict__ X, const unsigned short* __restrict__ Wt,
    unsigned short* __restrict__ kqv, unsigned short* __restrict__ vT) {
  __shared__ unsigned short As[2][64 * 32];   // 2 x 4 KB

  const int tid  = threadIdx.x;
  const int wave = tid >> 6, lane = tid & 63;
  const int quad = lane >> 4, l16 = lane & 15;

  const int m0    = blockIdx.x * 64;
  const int nbase = blockIdx.y * 192 + wave * 48;

  const int arow  = tid >> 3;        // 0..31
  const int acol4 = (tid & 7) * 4;   // fp32 col

  const float* Xr0 = X + (size_t)(m0 + arow) * C_ + acol4;
  const float* Xr1 = X + (size_t)(m0 + arow + 32) * C_ + acol4;

  const unsigned short* Bp[3];
#pragma unroll
  for (int nt = 0; nt < 3; ++nt)
    Bp[nt] = Wt + (size_t)(nbase + nt * 16 + l16) * C_ + quad * 8;

  // prologue: k=0 operands
  float4 a0 = *(const float4*)(Xr0);
  float4 a1 = *(const float4*)(Xr1);
  bf16x8 bcur[3];
#pragma unroll
  for (int nt = 0; nt < 3; ++nt) bcur[nt] = *(const bf16x8*)(Bp[nt]);

  floatx4 acc[4][3] = {};

  for (int k = 0; k < 64; ++k) {
    const int cur = k & 1;
    // convert & store A_k (uses a0/a1 loaded one iter ago)
    ushort4 u0, u1;
    u0.x = f2bf(a0.x); u0.y = f2bf(a0.y); u0.z = f2bf(a0.z); u0.w = f2bf(a0.w);
    u1.x = f2bf(a1.x); u1.y = f2bf(a1.y); u1.z = f2bf(a1.z); u1.w = f2bf(a1.w);
    *(ushort4*)&As[cur][arow * 32 + acol4]        = u0;
    *(ushort4*)&As[cur][(arow + 32) * 32 + acol4] = u1;
    __syncthreads();

    // issue next-iter loads (consumed just before/after NEXT barrier)
    bf16x8 bnxt[3] = {bcur[0], bcur[1], bcur[2]};
    if (k < 63) {
      const int kn = (k + 1) * 32;
      a0 = *(const float4*)(Xr0 + kn);
      a1 = *(const float4*)(Xr1 + kn);
#pragma unroll
      for (int nt = 0; nt < 3; ++nt)
        bnxt[nt] = *(const bf16x8*)(Bp[nt] + kn);
    }

    // compute: 4 ds_read_b128 + 12 MFMA
    bf16x8 af[4];
#pragma unroll
    for (int mt = 0; mt < 4; ++mt)
      af[mt] = *(const bf16x8*)&As[cur][(mt * 16 + l16) * 32 + quad * 8];
#pragma unroll
    for (int mt = 0; mt < 4; ++mt)
#pragma unroll
      for (int nt = 0; nt < 3; ++nt)
        acc[mt][nt] = __builtin_amdgcn_mfma_f32_16x16x32_bf16(
            af[mt], bcur[nt], acc[mt][nt], 0, 0, 0);
#pragma unroll
    for (int nt = 0; nt < 3; ++nt) bcur[nt] = bnxt[nt];
    // no second barrier: As is double-buffered
  }

  // epilogue: C/D layout col=lane&15 (n), row=quad*4+reg (m)
#pragma unroll
  for (int mt = 0; mt < 4; ++mt)
#pragma unroll
    for (int nt = 0; nt < 3; ++nt) {
      const int n = nbase + nt * 16 + l16;
      const bool isv = (nbase + nt * 16) >= 256;
#pragma unroll
      for (int r = 0; r < 4; ++r) {
        int m = m0 + mt * 16 + quad * 4 + r;
        unsigned short us = f2bf(acc[mt][nt][r]);
        kqv[(size_t)m * N_ + n] = us;
        if (isv) {
          int bb = m >> 8, tt = m & 255;
          vT[(size_t)bb * HS_ * T_ + (size_t)(n - 256) * T_ + tt] = us;
        }
      }
    }
}

// ---------------- Attention v4: block = (batch, 16-row t-tile), 4 waves -----
// Phase 1: wave p computes s-tiles st===p (mod 4) -> shared P (bf16) +
// partial row sums. One barrier. Phase 2: wave p owns h-cols [p*32, p*32+32):
// O = P @ V, disjoint h so no combine. 1024 light blocks -> high TLP.
__global__ __launch_bounds__(256) void attn_kernel(
    const unsigned short* __restrict__ kqv, const unsigned short* __restrict__ vT,
    float* __restrict__ out) {
  constexpr int PS = 264;                    // P row stride (shorts)
  __shared__ unsigned short P[16 * PS];      // 8.25 KB
  __shared__ float rsumw[4][16];

  const int tid  = threadIdx.x;
  const int p    = tid >> 6;                 // wave 0..3
  const int lane = tid & 63;
  const int quad = lane >> 4, l16 = lane & 15;
  const int tt = blockIdx.x;                 // 0..15
  const int b  = blockIdx.y;
  const int t0 = tt * 16;
  const float scale = 0.022097086912079612f; // 2048^-0.5
  const unsigned short* kq = kqv + (size_t)b * T_ * N_;

  // k fragments (A operand), rows t0..t0+15
  bf16x8 kf[4];
#pragma unroll
  for (int ks = 0; ks < 4; ++ks)
    kf[ks] = *(const bf16x8*)&kq[(size_t)(t0 + l16) * N_ + ks * 32 + quad * 8];

  // zero-fill s-tile tt+1 when the 32-wide PV k-step overlaps it
  if ((tt & 1) == 0 && p == ((tt + 1) & 3)) {
#pragma unroll
    for (int r = 0; r < 4; ++r)
      P[(quad * 4 + r) * PS + (tt + 1) * 16 + l16] = 0;
  }

  // ---- phase 1: S tiles -> exp/mask -> P, partial row sums
  float rsum[4] = {0.f, 0.f, 0.f, 0.f};
  for (int st = p; st <= tt; st += 4) {
    floatx4 a = {};
#pragma unroll
    for (int ks = 0; ks < 4; ++ks) {
      bf16x8 qf = *(const bf16x8*)&kq[(size_t)(st * 16 + l16) * N_ + HS_ +
                                      ks * 32 + quad * 8];
      a = __builtin_amdgcn_mfma_f32_16x16x32_bf16(kf[ks], qf, a, 0, 0, 0);
    }
    const int scol = st * 16 + l16;
#pragma unroll
    for (int r = 0; r < 4; ++r) {
      int trow = t0 + quad * 4 + r;
      float pv = (scol <= trow) ? __expf(a[r] * scale) : 0.f;
      rsum[r] += pv;
      P[(quad * 4 + r) * PS + scol] = f2bf(pv);
    }
  }
#pragma unroll
  for (int m = 1; m < 16; m <<= 1)
#pragma unroll
    for (int r = 0; r < 4; ++r)
      rsum[r] += __shfl_xor(rsum[r], m, 64);
  if (l16 == 0) {
#pragma unroll
    for (int r = 0; r < 4; ++r) rsumw[p][quad * 4 + r] = rsum[r];
  }
  __syncthreads();

  // ---- phase 2: O[:, p*32 .. p*32+31] = P @ V
  const unsigned short* vb = vT + (size_t)b * HS_ * T_;
  const int h0 = p * 32;
  const int nks = (tt + 2) >> 1;
  floatx4 oacc[2] = {};
  for (int ks = 0; ks < nks; ++ks) {
    bf16x8 pa = *(const bf16x8*)&P[l16 * PS + ks * 32 + quad * 8];
#pragma unroll
    for (int nt = 0; nt < 2; ++nt) {
      bf16x8 bv = *(const bf16x8*)&vb[(size_t)(h0 + nt * 16 + l16) * T_ +
                                      ks * 32 + quad * 8];
      oacc[nt] = __builtin_amdgcn_mfma_f32_16x16x32_bf16(pa, bv, oacc[nt], 0, 0, 0);
    }
  }

  float tot[4];
#pragma unroll
  for (int r = 0; r < 4; ++r) {
    int row = quad * 4 + r;
    tot[r] = rsumw[0][row] + rsumw[1][row] + rsumw[2][row] + rsumw[3][row];
  }
  float* ob = out + ((size_t)b * T_ + t0) * HS_;
#pragma unroll
  for (int nt = 0; nt < 2; ++nt)
#pragma unroll
    for (int r = 0; r < 4; ++r) {
      int row = quad * 4 + r;
      ob[(size_t)row * HS_ + h0 + nt * 16 + l16] = oacc[nt][r] / tot[r];
    }
}

extern "C" void kernel_launch(void* const* d_in, const int* in_sizes, int n_in,
                              void* d_out, int out_size, void* d_ws, size_t ws_size,
                              hipStream_t stream) {
  const float* x  = (const float*)d_in[0];
  const float* Wk = (const float*)d_in[1];
  const float* Wq = (const float*)d_in[2];
  const float* Wv = (const float*)d_in[3];
  float* out = (float*)d_out;

  char* ws = (char*)d_ws;
  unsigned short* Wt  = (unsigned short*)(ws);                        // 1.5 MB
  unsigned short* kqv = (unsigned short*)(ws + 1572864);              // 12 MB
  unsigned short* vT  = (unsigned short*)(ws + 1572864 + 12582912);   // 4 MB

  hipLaunchKernelGGL(wt_kernel, dim3(64, 4, 3), dim3(256), 0, stream, Wk, Wq, Wv, Wt);
  hipLaunchKernelGGL(qkv_gemm, dim3(256, 2), dim3(256), 0, stream, x, Wt, kqv, vT);
  hipLaunchKernelGGL(attn_kernel, dim3(16, 64), dim3(256), 0, stream, kqv, vT, out);
}